// Round 8
// baseline (947.669 us; speedup 1.0000x reference)
//
#include <hip/hip_runtime.h>

#define NB 8
#define SEQ 1024
#define EMB 512
#define FFD 2048
#define NROWS (NB*SEQ)   // 8192
#define LNEPS 1e-5f

typedef __bf16 bf16x8 __attribute__((ext_vector_type(8)));
typedef float f32x4 __attribute__((ext_vector_type(4)));

__device__ __forceinline__ unsigned short f2bf(float f){
  unsigned u = __builtin_bit_cast(unsigned, f);
  u += 0x7fffu + ((u>>16)&1u);
  return (unsigned short)(u>>16);
}
__device__ __forceinline__ bf16x8 ld_bf8(const unsigned short* p){
  return *(const bf16x8*)p;
}
__device__ __forceinline__ void async_copy16(const void* g, void* l){
  __builtin_amdgcn_global_load_lds((const __attribute__((address_space(1))) unsigned int*)g,
                                   (__attribute__((address_space(3))) unsigned int*)l,
                                   16, 0, 0);
}

// ---------------- block reductions (256 threads = 4 waves) ----------------
__device__ __forceinline__ float2 block_sum2(float a,float b){
  #pragma unroll
  for(int k=32;k>=1;k>>=1){ a += __shfl_xor(a,k,64); b += __shfl_xor(b,k,64); }
  __shared__ float sa[4], sb[4];
  int w = threadIdx.x>>6;
  __syncthreads();
  if((threadIdx.x&63)==0){ sa[w]=a; sb[w]=b; }
  __syncthreads();
  return make_float2(sa[0]+sa[1]+sa[2]+sa[3], sb[0]+sb[1]+sb[2]+sb[3]);
}

// ======== 128 x NT dbuf GEMM, XCD-swizzled 1D grid: C = A * B^T (+bias) ====
// Flat grid rt*ct*z. Decomposition puts all col-tiles of row-stripe g on
// XCD g (id%8 dispatch round-robin): per-XCD L2 working set = A-stripe
// (<=1MB) + B (<=2MB) < 4MB -> staging loads become L2 hits.
// 256 thr = 4 waves (2x2). BK=32, dbuf LDS, one barrier/iter, prefetch k+1
// issued post-barrier. BIAS only on z==0 (z = split-K). CAUSAL: kend=m0+128.
// global_load_lds LDS dest = lane*16B pattern (legal, m104/m108).
template<bool OUTBF16, bool RELU, bool BIAS, bool CAUSAL, int NT>
__global__ __launch_bounds__(256,4) void gemm_db(
    const unsigned short* __restrict__ Ag, const unsigned short* __restrict__ Bg,
    const float* __restrict__ bias, void* __restrict__ Cg,
    int K, int lda, int ldb, int ldc,
    long long strA, long long strB, long long strC,
    int rt, int ct)
{
  constexpr int NJ = NT/32;
  __shared__ unsigned short As[2][128*32];
  __shared__ unsigned short Bs[2][NT*32];
  const int id = blockIdx.x;
  const int rc = rt*ct;
  const int z  = id / rc;
  const int rem = id - z*rc;
  const int g = rem & 7, idx = rem >> 3;
  const int rpg = rt >> 3;                    // rt divisible by 8
  const int row = g*rpg + (idx % rpg);
  const int col = idx / rpg;
  const unsigned short* Ab = Ag + z*strA;
  const unsigned short* Bb = Bg + z*strB;
  const int m0 = row*128, n0 = col*NT;
  const int t = threadIdx.x;
  const int lane = t & 63, w = t >> 6;
  const int wy = w >> 1, wx = w & 1;
  const int q = lane >> 4, c = lane & 15;
  f32x4 acc[4][NJ] = {};
  const int kend = CAUSAL ? (m0 + 128) : K;
  const int srow = t >> 2;
  const int sk = (t & 3) * 8;                       // LDS chunk (elem off = 8t)
  const int gk = ((t & 3) ^ ((t >> 3) & 3)) * 8;    // swizzled global chunk
  const int rs = (q ^ ((c >> 1) & 3)) * 8;          // swizzled read chunk

#define STAGE(bi, kk) do { \
    async_copy16(Ab + (long long)(m0 + srow)*lda + (kk) + gk,      &As[bi][srow*32 + sk]); \
    async_copy16(Ab + (long long)(m0 + srow + 64)*lda + (kk) + gk, &As[bi][(srow+64)*32 + sk]); \
    async_copy16(Bb + (long long)(n0 + srow)*ldb + (kk) + gk,      &Bs[bi][srow*32 + sk]); \
    if(NT == 128) \
      async_copy16(Bb + (long long)(n0 + srow + 64)*ldb + (kk) + gk, &Bs[bi][(srow+64)*32 + sk]); \
  } while(0)

  STAGE(0, 0);
  int buf = 0;
  for(int k0 = 0; k0 < kend; k0 += 32, buf ^= 1){
    __syncthreads();                          // drains prefetch of `buf`
    if(k0 + 32 < kend) STAGE(buf^1, k0 + 32); // lands during compute below
    bf16x8 af[4], bfr[NJ];
    #pragma unroll
    for(int fi=0; fi<4; fi++) af[fi]  = ld_bf8(&As[buf][(wy*64 + fi*16 + c)*32 + rs]);
    #pragma unroll
    for(int fj=0; fj<NJ; fj++) bfr[fj] = ld_bf8(&Bs[buf][(wx*(NT/2) + fj*16 + c)*32 + rs]);
    #pragma unroll
    for(int fi=0; fi<4; fi++)
      #pragma unroll
      for(int fj=0; fj<NJ; fj++)
        acc[fi][fj] = __builtin_amdgcn_mfma_f32_16x16x32_bf16(af[fi], bfr[fj], acc[fi][fj], 0,0,0);
  }
#undef STAGE
  #pragma unroll
  for(int fi=0; fi<4; fi++){
    #pragma unroll
    for(int fj=0; fj<NJ; fj++){
      const int crow = m0 + wy*64 + fi*16 + q*4;
      const int ccol = n0 + wx*(NT/2) + fj*16 + c;
      const float bv = (BIAS && z==0) ? bias[ccol] : 0.f;
      #pragma unroll
      for(int r=0; r<4; r++){
        float v = acc[fi][fj][r] + bv;
        if(RELU) v = fmaxf(v, 0.f);
        long long off = z*strC + (long long)(crow+r)*ldc + ccol;
        if(OUTBF16) ((unsigned short*)Cg)[off] = f2bf(v);
        else        ((float*)Cg)[off] = v;
      }
    }
  }
}

// -------- attention pass 1: dpart[jt][b][h][i] = sum_{j in jt} exp(q_i.k_j/8) --
// Grid (8 j-tiles, 8 i-tiles, 64 bh). Plain stores (no atomics/memset):
// cross-wave (wx) pair combined through LDS.
__global__ __launch_bounds__(256) void qk_dsum(
    const unsigned short* __restrict__ qkv, float* __restrict__ dpart)
{
  __shared__ unsigned short As[128*32];
  __shared__ unsigned short Bs[128*32];
  __shared__ float red[2][128];
  const int bh = blockIdx.z, b = bh >> 3, h = bh & 7;
  const int i0 = blockIdx.y*128, j0 = blockIdx.x*128;
  const unsigned short* Ab = qkv + (long long)b*SEQ*1024 + h*64;
  const unsigned short* Bb = qkv + (long long)b*SEQ*1024 + 512 + h*64;
  const int t = threadIdx.x, lane = t & 63, w = t >> 6;
  const int wy = w >> 1, wx = w & 1, q = lane >> 4, c = lane & 15;
  f32x4 acc[4][4] = {};
  const int srow = t >> 2;
  const int sk = (t & 3) * 8;
  const int gk = ((t & 3) ^ ((t >> 3) & 3)) * 8;
  const int rs = (q ^ ((c >> 1) & 3)) * 8;
  #pragma unroll
  for(int k0 = 0; k0 < 64; k0 += 32){
    async_copy16(Ab + (long long)(i0 + srow)*1024 + k0 + gk,      As + srow*32 + sk);
    async_copy16(Ab + (long long)(i0 + srow + 64)*1024 + k0 + gk, As + (srow+64)*32 + sk);
    async_copy16(Bb + (long long)(j0 + srow)*1024 + k0 + gk,      Bs + srow*32 + sk);
    async_copy16(Bb + (long long)(j0 + srow + 64)*1024 + k0 + gk, Bs + (srow+64)*32 + sk);
    __syncthreads();
    bf16x8 af[4], bfr[4];
    #pragma unroll
    for(int fi=0; fi<4; fi++) af[fi]  = ld_bf8(As + (wy*64 + fi*16 + c)*32 + rs);
    #pragma unroll
    for(int fj=0; fj<4; fj++) bfr[fj] = ld_bf8(Bs + (wx*64 + fj*16 + c)*32 + rs);
    #pragma unroll
    for(int fi=0; fi<4; fi++)
      #pragma unroll
      for(int fj=0; fj<4; fj++)
        acc[fi][fj] = __builtin_amdgcn_mfma_f32_16x16x32_bf16(af[fi], bfr[fj], acc[fi][fj], 0,0,0);
    __syncthreads();
  }
  #pragma unroll
  for(int fi=0; fi<4; fi++){
    #pragma unroll
    for(int r=0; r<4; r++){
      float s = 0.f;
      #pragma unroll
      for(int fj=0; fj<4; fj++) s += __expf(acc[fi][fj][r]*0.125f);
      s += __shfl_xor(s,1,64); s += __shfl_xor(s,2,64);
      s += __shfl_xor(s,4,64); s += __shfl_xor(s,8,64);
      if(c == 0) red[wx][wy*64 + fi*16 + q*4 + r] = s;
    }
  }
  __syncthreads();
  if(t < 128)
    dpart[(((long long)blockIdx.x*NB + b)*8 + h)*SEQ + i0 + t] = red[0][t] + red[1][t];
}

// -------- attention pass 2: averaged A + pos/causal + 2nd softmax numerator ----
// inv8 from sum of 8 dpart slices; row-sum partials -> Dp[jt][b][i] (plain store;
// each row written once per block since waves cover disjoint rows).
__global__ __launch_bounds__(256) void attn_w(
    const unsigned short* __restrict__ qkv, const float* __restrict__ dpart,
    unsigned short* __restrict__ Wm, float* __restrict__ Dp)
{
  __shared__ unsigned short As[64*32];
  __shared__ unsigned short Bs[64*32];
  __shared__ float inv8[8][64];
  const int b = blockIdx.y;
  int x = blockIdx.x;
  int it = 0;
  while((it+1)*(it+2)/2 <= x) ++it;
  const int jt = x - it*(it+1)/2;
  const int i0 = it*64, j0 = jt*64;
  const int t = threadIdx.x, lane = t & 63, w = t >> 6;
  const int q = lane >> 4, c = lane & 15;
  for(int u = t; u < 512; u += 256){
    int h = u >> 6, r = u & 63;
    float s = 0.f;
    #pragma unroll
    for(int j2 = 0; j2 < 8; j2++)
      s += dpart[(((long long)j2*NB + b)*8 + h)*SEQ + i0 + r];
    inv8[h][r] = 1.f/(8.f*s);
  }
  const unsigned short* Qb = qkv + (long long)b*SEQ*1024;
  const int srow = t >> 2;
  const int sk = (t & 3) * 8;
  const int gk = ((t & 3) ^ ((t >> 3) & 3)) * 8;
  const int rs = (q ^ ((c >> 1) & 3)) * 8;
  f32x4 at[4] = {};
  for(int h = 0; h < 8; h++){
    f32x4 l[4] = {};
    #pragma unroll
    for(int k0 = 0; k0 < 64; k0 += 32){
      __syncthreads();
      async_copy16(Qb + (long long)(i0 + srow)*1024 + h*64 + k0 + gk,       As + srow*32 + sk);
      async_copy16(Qb + (long long)(j0 + srow)*1024 + 512 + h*64 + k0 + gk, Bs + srow*32 + sk);
      __syncthreads();
      bf16x8 af = ld_bf8(As + (w*16 + c)*32 + rs);
      bf16x8 bfr[4];
      #pragma unroll
      for(int fj=0; fj<4; fj++) bfr[fj] = ld_bf8(Bs + (fj*16 + c)*32 + rs);
      #pragma unroll
      for(int fj=0; fj<4; fj++)
        l[fj] = __builtin_amdgcn_mfma_f32_16x16x32_bf16(af, bfr[fj], l[fj], 0,0,0);
    }
    #pragma unroll
    for(int r=0; r<4; r++){
      float iv = inv8[h][w*16 + q*4 + r];
      #pragma unroll
      for(int fj=0; fj<4; fj++)
        at[fj][r] += __expf(l[fj][r]*0.125f)*iv;
    }
  }
  float Dacc[4] = {};
  #pragma unroll
  for(int fj=0; fj<4; fj++){
    #pragma unroll
    for(int r=0; r<4; r++){
      const int i = i0 + w*16 + q*4 + r;
      const int j = j0 + fj*16 + c;
      float wv = 0.f;
      if(j <= i) wv = __expf(at[fj][r] + __expf((float)(j - i)*0.1f));
      Wm[((long long)(b*SEQ + i))*SEQ + j] = f2bf(wv);
      Dacc[r] += wv;
    }
  }
  #pragma unroll
  for(int r=0; r<4; r++){
    Dacc[r] += __shfl_xor(Dacc[r],1,64); Dacc[r] += __shfl_xor(Dacc[r],2,64);
    Dacc[r] += __shfl_xor(Dacc[r],4,64); Dacc[r] += __shfl_xor(Dacc[r],8,64);
    if(c == 0)
      Dp[((long long)jt*NB + b)*SEQ + i0 + w*16 + q*4 + r] = Dacc[r];
  }
}

// ------- LDS-tiled transpose: Xb [8192,512] -> XT [512,8192] -------
__global__ __launch_bounds__(256) void transpose_bf16(
    const unsigned short* __restrict__ src, unsigned short* __restrict__ dst)
{
  __shared__ unsigned short tile[64*65];
  const int bx = blockIdx.x;
  const int by = blockIdx.y;
  const int t = threadIdx.x;
  #pragma unroll
  for(int p=0; p<2; p++){
    int idx = t + p*256;
    int r = idx >> 3, cc = (idx & 7)*8;
    alignas(16) unsigned short e[8];
    *(uint4*)e = *(const uint4*)(src + (long long)(by*64 + r)*512 + bx*64 + cc);
    #pragma unroll
    for(int u=0; u<8; u++) tile[r*65 + cc + u] = e[u];
  }
  __syncthreads();
  #pragma unroll
  for(int p=0; p<2; p++){
    int idx = t + p*256;
    int r2 = idx >> 3, c2 = (idx & 7)*8;
    alignas(16) unsigned short e[8];
    #pragma unroll
    for(int u=0; u<8; u++) e[u] = tile[(c2+u)*65 + r2];
    *(uint4*)(dst + (long long)(bx*64 + r2)*8192 + by*64 + c2) = *(const uint4*)e;
  }
}

// ------- fused residual(+1/sum(Dp) scale) + LN1 + LN2; writes fp32 + bf16 ------
__global__ __launch_bounds__(256) void residual_ln2(
    const float* __restrict__ X, const float* __restrict__ SA,
    const float* __restrict__ Dp,
    const float* __restrict__ g1, const float* __restrict__ b1,
    const float* __restrict__ g2, const float* __restrict__ b2,
    float* __restrict__ XO, unsigned short* __restrict__ Xb)
{
  const long long row = blockIdx.x;
  const int t = threadIdx.x;
  const int b = (int)(row >> 10), i = (int)(row & 1023), itile = i >> 6;
  float Ds = 0.f;
  for(int jt = 0; jt <= itile; jt++)
    Ds += Dp[((long long)jt*NB + b)*SEQ + i];
  const float s = 1.f/Ds;
  float v0 = X[row*EMB + t]       + SA[row*EMB + t]*s;
  float v1 = X[row*EMB + t + 256] + SA[row*EMB + t + 256]*s;
  float2 ss = block_sum2(v0+v1, v0*v0+v1*v1);
  float mean = ss.x*(1.f/EMB);
  float var  = ss.y*(1.f/EMB) - mean*mean;
  float rstd = rsqrtf(var + LNEPS);
  float y0 = (v0-mean)*rstd*g1[t]     + b1[t];
  float y1 = (v1-mean)*rstd*g1[t+256] + b1[t+256];
  ss = block_sum2(y0+y1, y0*y0+y1*y1);
  mean = ss.x*(1.f/EMB);
  var  = ss.y*(1.f/EMB) - mean*mean;
  rstd = rsqrtf(var + LNEPS);
  float o0 = (y0-mean)*rstd*g2[t]     + b2[t];
  float o1 = (y1-mean)*rstd*g2[t+256] + b2[t+256];
  XO[row*EMB + t] = o0;       XO[row*EMB + t + 256] = o1;
  Xb[row*EMB + t] = f2bf(o0); Xb[row*EMB + t + 256] = f2bf(o1);
}

// ------- residual(2 partials) + LN; writes fp32 + bf16 -------
__global__ __launch_bounds__(256) void residual_ln(
    const float* __restrict__ X, const float* __restrict__ R1,
    const float* __restrict__ R2,
    const float* __restrict__ g, const float* __restrict__ b,
    float* __restrict__ XO, unsigned short* __restrict__ Xb)
{
  const long long row = blockIdx.x;
  const int t = threadIdx.x;
  float v0 = X[row*EMB + t]       + R1[row*EMB + t]       + R2[row*EMB + t];
  float v1 = X[row*EMB + t + 256] + R1[row*EMB + t + 256] + R2[row*EMB + t + 256];
  float2 ss = block_sum2(v0+v1, v0*v0+v1*v1);
  float mean = ss.x*(1.f/EMB);
  float var  = ss.y*(1.f/EMB) - mean*mean;
  float rstd = rsqrtf(var + LNEPS);
  float o0 = (v0-mean)*rstd*g[t]     + b[t];
  float o1 = (v1-mean)*rstd*g[t+256] + b[t+256];
  XO[row*EMB + t] = o0;       XO[row*EMB + t + 256] = o1;
  Xb[row*EMB + t] = f2bf(o0); Xb[row*EMB + t + 256] = f2bf(o1);
}

// ------- initial x -> X fp32 copy + bf16 -------
__global__ __launch_bounds__(256) void init_x(
    const float* __restrict__ in, float* __restrict__ XO,
    unsigned short* __restrict__ Xb)
{
  const long long row = blockIdx.x;
  const int t = threadIdx.x;
  float v0 = in[row*EMB + t];
  float v1 = in[row*EMB + t + 256];
  XO[row*EMB + t] = v0;       XO[row*EMB + t + 256] = v1;
  Xb[row*EMB + t] = f2bf(v0); Xb[row*EMB + t + 256] = f2bf(v1);
}

// ------- all weights fp32 -> bf16 in ONE kernel -------
// seg0: Wqkv q/k rows (first 1024 of each 1536) -> 524288 float4-chunks
// seg1: W1 (4M elems) -> 1048576 chunks; seg2: W2 -> 1048576 chunks
__global__ __launch_bounds__(256) void cvt_all(
    const float* __restrict__ Wqkv, const float* __restrict__ W1,
    const float* __restrict__ W2, unsigned short* __restrict__ Wqkvb,
    unsigned short* __restrict__ W1b, unsigned short* __restrict__ W2b)
{
  const long long id = (long long)blockIdx.x*256 + threadIdx.x;
  const long long n0 = 524288, n1 = 1048576;
  float4 v; unsigned short* dst;
  if(id < n0){
    long long i = id*4;
    int layer = (int)(i >> 19);
    long long within = i & ((1LL<<19)-1);
    v = *(const float4*)(Wqkv + (long long)layer*1536*512 + within);
    dst = Wqkvb + i;
  } else if(id < n0 + n1){
    long long i = (id - n0)*4;
    v = *(const float4*)(W1 + i);
    dst = W1b + i;
  } else {
    long long i = (id - n0 - n1)*4;
    v = *(const float4*)(W2 + i);
    dst = W2b + i;
  }
  *(ushort4*)dst = make_ushort4(f2bf(v.x), f2bf(v.y), f2bf(v.z), f2bf(v.w));
}

extern "C" void kernel_launch(void* const* d_in, const int* in_sizes, int n_in,
                              void* d_out, int out_size, void* d_ws, size_t ws_size,
                              hipStream_t stream)
{
  const float* x_in = (const float*)d_in[0];
  const float* Wqkv = (const float*)d_in[1];
  const float* bqkv = (const float*)d_in[2];
  const float* W1   = (const float*)d_in[3];
  const float* b1   = (const float*)d_in[4];
  const float* W2   = (const float*)d_in[5];
  const float* b2   = (const float*)d_in[6];
  const float* g1   = (const float*)d_in[7];
  const float* bt1  = (const float*)d_in[8];
  const float* g2   = (const float*)d_in[9];
  const float* bt2  = (const float*)d_in[10];
  const float* g3   = (const float*)d_in[11];
  const float* bt3  = (const float*)d_in[12];

  float* X = (float*)d_out;                               // [8192,512] fp32

  char* ws = (char*)d_ws;
  unsigned short* qkv    = (unsigned short*)(ws);                       // 16MB [8192,1024] bf16 (q,k)
  unsigned short* hbuf   = (unsigned short*)(ws + ((size_t)16<<20));    // 32MB [8192,2048] bf16
  unsigned short* Wm     = (unsigned short*)(ws + ((size_t)48<<20));    // 16MB [8,1024,1024] bf16
  float*          tmp    = (float*)         (ws + ((size_t)64<<20));    // 16MB [8192,512] fp32 (sa / ffn2 p0)
  float*          tmp2   = (float*)         (ws + ((size_t)80<<20));    // 16MB ffn2 p1
  unsigned short* Xb     = (unsigned short*)(ws + ((size_t)96<<20));    // 8MB  [8192,512] bf16
  unsigned short* XT     = (unsigned short*)(ws + ((size_t)104<<20));   // 8MB  [512,8192] bf16
  unsigned short* Wqkvb  = (unsigned short*)(ws + ((size_t)112<<20));   // 4MB  [4,1024,512]
  unsigned short* W1b    = (unsigned short*)(ws + ((size_t)118<<20));   // 8MB
  unsigned short* W2b    = (unsigned short*)(ws + ((size_t)126<<20));   // 8MB
  float*          dpart  = (float*)         (ws + ((size_t)134<<20));   // 2MB  [8][8][8][1024]
  float*          Dp     = (float*)         (ws + ((size_t)136<<20));   // 512KB [16][8][1024]

  // weight conversions (same work every call): one kernel, 3 segments
  cvt_all<<<(524288 + 2*1048576)/256, 256, 0, stream>>>(Wqkv, W1, W2, Wqkvb, W1b, W2b);
  init_x<<<NROWS, 256, 0, stream>>>(x_in, X, Xb);
  transpose_bf16<<<dim3(8,128), 256, 0, stream>>>(Xb, XT);

  for(int d=0; d<4; d++){
    // qk = X * Wqkv[0:1024]^T + bqkv   (128x128 dbuf, XCD-swizzled, 512 blocks)
    gemm_db<true,false,true,false,128><<<dim3(512), 256, 0, stream>>>(
        Xb, Wqkvb + (size_t)d*1024*EMB, bqkv + (size_t)d*1536, qkv,
        EMB, EMB, EMB, 1024, 0, 0, 0, 64, 8);

    // per-head per-j-tile softmax denominator partials (no atomics)
    qk_dsum<<<dim3(8, 8, 64), 256, 0, stream>>>(qkv, dpart);

    // averaged A + causal/pos re-softmax numerator -> Wm, Dp partials
    attn_w<<<dim3(136, NB), 256, 0, stream>>>(qkv, dpart, Wm, Dp);

    // sa = W @ x  (B = XT per batch, causal K limit), 128x64 dbuf, 512 blocks
    gemm_db<false,false,false,true,64><<<dim3(512), 256, 0, stream>>>(
        Wm, XT, nullptr, tmp,
        SEQ, SEQ, NROWS, EMB,
        (long long)SEQ*SEQ, 1024, (long long)SEQ*EMB, 8, 8);

    // x = LN2(LN1(x + sa/sum(Dp)))
    residual_ln2<<<NROWS, 256, 0, stream>>>(X, tmp, Dp,
        g1 + d*EMB, bt1 + d*EMB, g2 + d*EMB, bt2 + d*EMB, X, Xb);

    // h = relu(x*W1^T + b1)   (1024 blocks)
    gemm_db<true,true,true,false,128><<<dim3(1024), 256, 0, stream>>>(
        Xb, W1b + (size_t)d*FFD*EMB, b1 + (size_t)d*FFD, hbuf,
        EMB, EMB, EMB, FFD, 0, 0, 0, 64, 16);

    // ff = h*W2^T + b2, split-K=2 (partials tmp, tmp2; bias on z==0), 512 blocks
    gemm_db<false,false,true,false,128><<<dim3(512), 256, 0, stream>>>(
        hbuf, W2b + (size_t)d*EMB*FFD, b2 + (size_t)d*EMB, tmp,
        1024, FFD, FFD, EMB,
        1024, 1024, (long long)NROWS*EMB, 64, 4);

    // x = LN3(x + ff0 + ff1)
    residual_ln<<<NROWS, 256, 0, stream>>>(X, tmp, tmp2,
        g3 + d*EMB, bt3 + d*EMB, X, Xb);
    transpose_bf16<<<dim3(8,128), 256, 0, stream>>>(Xb, XT);
  }
}

// Round 9
// 890.197 us; speedup vs baseline: 1.0646x; 1.0646x over previous
//
#include <hip/hip_runtime.h>

#define NB 8
#define SEQ 1024
#define EMB 512
#define FFD 2048
#define NROWS (NB*SEQ)   // 8192
#define LNEPS 1e-5f

typedef __bf16 bf16x8 __attribute__((ext_vector_type(8)));
typedef float f32x4 __attribute__((ext_vector_type(4)));

__device__ __forceinline__ unsigned short f2bf(float f){
  unsigned u = __builtin_bit_cast(unsigned, f);
  u += 0x7fffu + ((u>>16)&1u);
  return (unsigned short)(u>>16);
}
__device__ __forceinline__ bf16x8 ld_bf8(const unsigned short* p){
  return *(const bf16x8*)p;
}
__device__ __forceinline__ void async_copy16(const void* g, void* l){
  __builtin_amdgcn_global_load_lds((const __attribute__((address_space(1))) unsigned int*)g,
                                   (__attribute__((address_space(3))) unsigned int*)l,
                                   16, 0, 0);
}

// ---------------- block reductions (256 threads = 4 waves) ----------------
__device__ __forceinline__ float2 block_sum2(float a,float b){
  #pragma unroll
  for(int k=32;k>=1;k>>=1){ a += __shfl_xor(a,k,64); b += __shfl_xor(b,k,64); }
  __shared__ float sa[4], sb[4];
  int w = threadIdx.x>>6;
  __syncthreads();
  if((threadIdx.x&63)==0){ sa[w]=a; sb[w]=b; }
  __syncthreads();
  return make_float2(sa[0]+sa[1]+sa[2]+sa[3], sb[0]+sb[1]+sb[2]+sb[3]);
}

// ======== 128 x NT dbuf GEMM, XCD-swizzled 1D grid: C = A * B^T (+bias) ====
template<bool OUTBF16, bool RELU, bool BIAS, bool CAUSAL, int NT>
__global__ __launch_bounds__(256,4) void gemm_db(
    const unsigned short* __restrict__ Ag, const unsigned short* __restrict__ Bg,
    const float* __restrict__ bias, void* __restrict__ Cg,
    int K, int lda, int ldb, int ldc,
    long long strA, long long strB, long long strC,
    int rt, int ct)
{
  constexpr int NJ = NT/32;
  __shared__ unsigned short As[2][128*32];
  __shared__ unsigned short Bs[2][NT*32];
  const int id = blockIdx.x;
  const int rc = rt*ct;
  const int z  = id / rc;
  const int rem = id - z*rc;
  const int g = rem & 7, idx = rem >> 3;
  const int rpg = rt >> 3;                    // rt divisible by 8
  const int row = g*rpg + (idx % rpg);
  const int col = idx / rpg;
  const unsigned short* Ab = Ag + z*strA;
  const unsigned short* Bb = Bg + z*strB;
  const int m0 = row*128, n0 = col*NT;
  const int t = threadIdx.x;
  const int lane = t & 63, w = t >> 6;
  const int wy = w >> 1, wx = w & 1;
  const int q = lane >> 4, c = lane & 15;
  f32x4 acc[4][NJ] = {};
  const int kend = CAUSAL ? (m0 + 128) : K;
  const int srow = t >> 2;
  const int sk = (t & 3) * 8;                       // LDS chunk (elem off = 8t)
  const int gk = ((t & 3) ^ ((t >> 3) & 3)) * 8;    // swizzled global chunk
  const int rs = (q ^ ((c >> 1) & 3)) * 8;          // swizzled read chunk

#define STAGE(bi, kk) do { \
    async_copy16(Ab + (long long)(m0 + srow)*lda + (kk) + gk,      &As[bi][srow*32 + sk]); \
    async_copy16(Ab + (long long)(m0 + srow + 64)*lda + (kk) + gk, &As[bi][(srow+64)*32 + sk]); \
    async_copy16(Bb + (long long)(n0 + srow)*ldb + (kk) + gk,      &Bs[bi][srow*32 + sk]); \
    if(NT == 128) \
      async_copy16(Bb + (long long)(n0 + srow + 64)*ldb + (kk) + gk, &Bs[bi][(srow+64)*32 + sk]); \
  } while(0)

  STAGE(0, 0);
  int buf = 0;
  for(int k0 = 0; k0 < kend; k0 += 32, buf ^= 1){
    __syncthreads();                          // drains prefetch of `buf`
    if(k0 + 32 < kend) STAGE(buf^1, k0 + 32); // lands during compute below
    bf16x8 af[4], bfr[NJ];
    #pragma unroll
    for(int fi=0; fi<4; fi++) af[fi]  = ld_bf8(&As[buf][(wy*64 + fi*16 + c)*32 + rs]);
    #pragma unroll
    for(int fj=0; fj<NJ; fj++) bfr[fj] = ld_bf8(&Bs[buf][(wx*(NT/2) + fj*16 + c)*32 + rs]);
    #pragma unroll
    for(int fi=0; fi<4; fi++)
      #pragma unroll
      for(int fj=0; fj<NJ; fj++)
        acc[fi][fj] = __builtin_amdgcn_mfma_f32_16x16x32_bf16(af[fi], bfr[fj], acc[fi][fj], 0,0,0);
  }
#undef STAGE
  #pragma unroll
  for(int fi=0; fi<4; fi++){
    #pragma unroll
    for(int fj=0; fj<NJ; fj++){
      const int crow = m0 + wy*64 + fi*16 + q*4;
      const int ccol = n0 + wx*(NT/2) + fj*16 + c;
      const float bv = (BIAS && z==0) ? bias[ccol] : 0.f;
      #pragma unroll
      for(int r=0; r<4; r++){
        float v = acc[fi][fj][r] + bv;
        if(RELU) v = fmaxf(v, 0.f);
        long long off = z*strC + (long long)(crow+r)*ldc + ccol;
        if(OUTBF16) ((unsigned short*)Cg)[off] = f2bf(v);
        else        ((float*)Cg)[off] = v;
      }
    }
  }
}

// -------- attention pass 1: dpart[jt][b][h][i] = sum_{j in jt} exp(q_i.k_j/8) --
__global__ __launch_bounds__(256) void qk_dsum(
    const unsigned short* __restrict__ qkv, float* __restrict__ dpart)
{
  __shared__ unsigned short As[128*32];
  __shared__ unsigned short Bs[128*32];
  __shared__ float red[2][128];
  const int bh = blockIdx.z, b = bh >> 3, h = bh & 7;
  const int i0 = blockIdx.y*128, j0 = blockIdx.x*128;
  const unsigned short* Ab = qkv + (long long)b*SEQ*1024 + h*64;
  const unsigned short* Bb = qkv + (long long)b*SEQ*1024 + 512 + h*64;
  const int t = threadIdx.x, lane = t & 63, w = t >> 6;
  const int wy = w >> 1, wx = w & 1, q = lane >> 4, c = lane & 15;
  f32x4 acc[4][4] = {};
  const int srow = t >> 2;
  const int sk = (t & 3) * 8;
  const int gk = ((t & 3) ^ ((t >> 3) & 3)) * 8;
  const int rs = (q ^ ((c >> 1) & 3)) * 8;
  #pragma unroll
  for(int k0 = 0; k0 < 64; k0 += 32){
    async_copy16(Ab + (long long)(i0 + srow)*1024 + k0 + gk,      As + srow*32 + sk);
    async_copy16(Ab + (long long)(i0 + srow + 64)*1024 + k0 + gk, As + (srow+64)*32 + sk);
    async_copy16(Bb + (long long)(j0 + srow)*1024 + k0 + gk,      Bs + srow*32 + sk);
    async_copy16(Bb + (long long)(j0 + srow + 64)*1024 + k0 + gk, Bs + (srow+64)*32 + sk);
    __syncthreads();
    bf16x8 af[4], bfr[4];
    #pragma unroll
    for(int fi=0; fi<4; fi++) af[fi]  = ld_bf8(As + (wy*64 + fi*16 + c)*32 + rs);
    #pragma unroll
    for(int fj=0; fj<4; fj++) bfr[fj] = ld_bf8(Bs + (wx*64 + fj*16 + c)*32 + rs);
    #pragma unroll
    for(int fi=0; fi<4; fi++)
      #pragma unroll
      for(int fj=0; fj<4; fj++)
        acc[fi][fj] = __builtin_amdgcn_mfma_f32_16x16x32_bf16(af[fi], bfr[fj], acc[fi][fj], 0,0,0);
    __syncthreads();
  }
  #pragma unroll
  for(int fi=0; fi<4; fi++){
    #pragma unroll
    for(int r=0; r<4; r++){
      float s = 0.f;
      #pragma unroll
      for(int fj=0; fj<4; fj++) s += __expf(acc[fi][fj][r]*0.125f);
      s += __shfl_xor(s,1,64); s += __shfl_xor(s,2,64);
      s += __shfl_xor(s,4,64); s += __shfl_xor(s,8,64);
      if(c == 0) red[wx][wy*64 + fi*16 + q*4 + r] = s;
    }
  }
  __syncthreads();
  if(t < 128)
    dpart[(((long long)blockIdx.x*NB + b)*8 + h)*SEQ + i0 + t] = red[0][t] + red[1][t];
}

// -------- attention pass 2: averaged A + pos/causal + 2nd softmax numerator ----
// Flattened (head, k-half) loop: 16 dbuf iterations, ONE barrier each;
// prefetch of n+1 issued post-barrier, flies during MFMA+exp of n.
__global__ __launch_bounds__(256) void attn_w(
    const unsigned short* __restrict__ qkv, const float* __restrict__ dpart,
    unsigned short* __restrict__ Wm, float* __restrict__ Dp)
{
  __shared__ unsigned short As[2][64*32];
  __shared__ unsigned short Bs[2][64*32];
  __shared__ float inv8[8][64];
  const int b = blockIdx.y;
  int x = blockIdx.x;
  int it = 0;
  while((it+1)*(it+2)/2 <= x) ++it;
  const int jt = x - it*(it+1)/2;
  const int i0 = it*64, j0 = jt*64;
  const int t = threadIdx.x, lane = t & 63, w = t >> 6;
  const int q = lane >> 4, c = lane & 15;
  for(int u = t; u < 512; u += 256){
    int h = u >> 6, r = u & 63;
    float s = 0.f;
    #pragma unroll
    for(int j2 = 0; j2 < 8; j2++)
      s += dpart[(((long long)j2*NB + b)*8 + h)*SEQ + i0 + r];
    inv8[h][r] = 1.f/(8.f*s);
  }
  const unsigned short* Qb = qkv + (long long)b*SEQ*1024;
  const int srow = t >> 2;
  const int sk = (t & 3) * 8;
  const int gk = ((t & 3) ^ ((t >> 3) & 3)) * 8;
  const int rs = (q ^ ((c >> 1) & 3)) * 8;

  // iteration n: head = n>>1, k-half = (n&1)*32
#define ASTAGE(bi, n) do { \
    const int hh = (n) >> 1, kk = ((n)&1)*32; \
    async_copy16(Qb + (long long)(i0 + srow)*1024 + hh*64 + kk + gk,       &As[bi][srow*32 + sk]); \
    async_copy16(Qb + (long long)(j0 + srow)*1024 + 512 + hh*64 + kk + gk, &Bs[bi][srow*32 + sk]); \
  } while(0)

  f32x4 at[4] = {};
  f32x4 l[4] = {};
  ASTAGE(0, 0);
  int buf = 0;
  for(int n = 0; n < 16; n++, buf ^= 1){
    __syncthreads();                       // drains prefetch of `buf`
    if(n + 1 < 16) ASTAGE(buf^1, n+1);     // lands during compute below
    bf16x8 af = ld_bf8(&As[buf][(w*16 + c)*32 + rs]);
    bf16x8 bfr[4];
    #pragma unroll
    for(int fj=0; fj<4; fj++) bfr[fj] = ld_bf8(&Bs[buf][(fj*16 + c)*32 + rs]);
    #pragma unroll
    for(int fj=0; fj<4; fj++)
      l[fj] = __builtin_amdgcn_mfma_f32_16x16x32_bf16(af, bfr[fj], l[fj], 0,0,0);
    if(n & 1){
      const int h = n >> 1;
      #pragma unroll
      for(int r=0; r<4; r++){
        float iv = inv8[h][w*16 + q*4 + r];
        #pragma unroll
        for(int fj=0; fj<4; fj++)
          at[fj][r] += __expf(l[fj][r]*0.125f)*iv;
      }
      #pragma unroll
      for(int fj=0; fj<4; fj++) l[fj] = f32x4{0.f,0.f,0.f,0.f};
    }
  }
#undef ASTAGE
  float Dacc[4] = {};
  #pragma unroll
  for(int fj=0; fj<4; fj++){
    #pragma unroll
    for(int r=0; r<4; r++){
      const int i = i0 + w*16 + q*4 + r;
      const int j = j0 + fj*16 + c;
      float wv = 0.f;
      if(j <= i) wv = __expf(at[fj][r] + __expf((float)(j - i)*0.1f));
      Wm[((long long)(b*SEQ + i))*SEQ + j] = f2bf(wv);
      Dacc[r] += wv;
    }
  }
  #pragma unroll
  for(int r=0; r<4; r++){
    Dacc[r] += __shfl_xor(Dacc[r],1,64); Dacc[r] += __shfl_xor(Dacc[r],2,64);
    Dacc[r] += __shfl_xor(Dacc[r],4,64); Dacc[r] += __shfl_xor(Dacc[r],8,64);
    if(c == 0)
      Dp[((long long)jt*NB + b)*SEQ + i0 + w*16 + q*4 + r] = Dacc[r];
  }
}

// ------- LDS-tiled transpose: Xb [8192,512] -> XT [512,8192] -------
__global__ __launch_bounds__(256) void transpose_bf16(
    const unsigned short* __restrict__ src, unsigned short* __restrict__ dst)
{
  __shared__ unsigned short tile[64*65];
  const int bx = blockIdx.x;
  const int by = blockIdx.y;
  const int t = threadIdx.x;
  #pragma unroll
  for(int p=0; p<2; p++){
    int idx = t + p*256;
    int r = idx >> 3, cc = (idx & 7)*8;
    alignas(16) unsigned short e[8];
    *(uint4*)e = *(const uint4*)(src + (long long)(by*64 + r)*512 + bx*64 + cc);
    #pragma unroll
    for(int u=0; u<8; u++) tile[r*65 + cc + u] = e[u];
  }
  __syncthreads();
  #pragma unroll
  for(int p=0; p<2; p++){
    int idx = t + p*256;
    int r2 = idx >> 3, c2 = (idx & 7)*8;
    alignas(16) unsigned short e[8];
    #pragma unroll
    for(int u=0; u<8; u++) e[u] = tile[(c2+u)*65 + r2];
    *(uint4*)(dst + (long long)(bx*64 + r2)*8192 + by*64 + c2) = *(const uint4*)e;
  }
}

// ------- fused residual(+1/sum(Dp) scale) + LN1 + LN2; writes fp32 + bf16 ------
__global__ __launch_bounds__(256) void residual_ln2(
    const float* __restrict__ X, const float* __restrict__ SA,
    const float* __restrict__ Dp,
    const float* __restrict__ g1, const float* __restrict__ b1,
    const float* __restrict__ g2, const float* __restrict__ b2,
    float* __restrict__ XO, unsigned short* __restrict__ Xb)
{
  const long long row = blockIdx.x;
  const int t = threadIdx.x;
  const int b = (int)(row >> 10), i = (int)(row & 1023), itile = i >> 6;
  float Ds = 0.f;
  for(int jt = 0; jt <= itile; jt++)
    Ds += Dp[((long long)jt*NB + b)*SEQ + i];
  const float s = 1.f/Ds;
  float v0 = X[row*EMB + t]       + SA[row*EMB + t]*s;
  float v1 = X[row*EMB + t + 256] + SA[row*EMB + t + 256]*s;
  float2 ss = block_sum2(v0+v1, v0*v0+v1*v1);
  float mean = ss.x*(1.f/EMB);
  float var  = ss.y*(1.f/EMB) - mean*mean;
  float rstd = rsqrtf(var + LNEPS);
  float y0 = (v0-mean)*rstd*g1[t]     + b1[t];
  float y1 = (v1-mean)*rstd*g1[t+256] + b1[t+256];
  ss = block_sum2(y0+y1, y0*y0+y1*y1);
  mean = ss.x*(1.f/EMB);
  var  = ss.y*(1.f/EMB) - mean*mean;
  rstd = rsqrtf(var + LNEPS);
  float o0 = (y0-mean)*rstd*g2[t]     + b2[t];
  float o1 = (y1-mean)*rstd*g2[t+256] + b2[t+256];
  XO[row*EMB + t] = o0;       XO[row*EMB + t + 256] = o1;
  Xb[row*EMB + t] = f2bf(o0); Xb[row*EMB + t + 256] = f2bf(o1);
}

// ------- residual(2 partials) + LN; writes fp32 + bf16 -------
__global__ __launch_bounds__(256) void residual_ln(
    const float* __restrict__ X, const float* __restrict__ R1,
    const float* __restrict__ R2,
    const float* __restrict__ g, const float* __restrict__ b,
    float* __restrict__ XO, unsigned short* __restrict__ Xb)
{
  const long long row = blockIdx.x;
  const int t = threadIdx.x;
  float v0 = X[row*EMB + t]       + R1[row*EMB + t]       + R2[row*EMB + t];
  float v1 = X[row*EMB + t + 256] + R1[row*EMB + t + 256] + R2[row*EMB + t + 256];
  float2 ss = block_sum2(v0+v1, v0*v0+v1*v1);
  float mean = ss.x*(1.f/EMB);
  float var  = ss.y*(1.f/EMB) - mean*mean;
  float rstd = rsqrtf(var + LNEPS);
  float o0 = (v0-mean)*rstd*g[t]     + b[t];
  float o1 = (v1-mean)*rstd*g[t+256] + b[t+256];
  XO[row*EMB + t] = o0;       XO[row*EMB + t + 256] = o1;
  Xb[row*EMB + t] = f2bf(o0); Xb[row*EMB + t + 256] = f2bf(o1);
}

// ------- initial x -> X fp32 copy + bf16 -------
__global__ __launch_bounds__(256) void init_x(
    const float* __restrict__ in, float* __restrict__ XO,
    unsigned short* __restrict__ Xb)
{
  const long long row = blockIdx.x;
  const int t = threadIdx.x;
  float v0 = in[row*EMB + t];
  float v1 = in[row*EMB + t + 256];
  XO[row*EMB + t] = v0;       XO[row*EMB + t + 256] = v1;
  Xb[row*EMB + t] = f2bf(v0); Xb[row*EMB + t + 256] = f2bf(v1);
}

// ------- all weights fp32 -> bf16 in ONE kernel -------
__global__ __launch_bounds__(256) void cvt_all(
    const float* __restrict__ Wqkv, const float* __restrict__ W1,
    const float* __restrict__ W2, unsigned short* __restrict__ Wqkvb,
    unsigned short* __restrict__ W1b, unsigned short* __restrict__ W2b)
{
  const long long id = (long long)blockIdx.x*256 + threadIdx.x;
  const long long n0 = 524288, n1 = 1048576;
  float4 v; unsigned short* dst;
  if(id < n0){
    long long i = id*4;
    int layer = (int)(i >> 19);
    long long within = i & ((1LL<<19)-1);
    v = *(const float4*)(Wqkv + (long long)layer*1536*512 + within);
    dst = Wqkvb + i;
  } else if(id < n0 + n1){
    long long i = (id - n0)*4;
    v = *(const float4*)(W1 + i);
    dst = W1b + i;
  } else {
    long long i = (id - n0 - n1)*4;
    v = *(const float4*)(W2 + i);
    dst = W2b + i;
  }
  *(ushort4*)dst = make_ushort4(f2bf(v.x), f2bf(v.y), f2bf(v.z), f2bf(v.w));
}

extern "C" void kernel_launch(void* const* d_in, const int* in_sizes, int n_in,
                              void* d_out, int out_size, void* d_ws, size_t ws_size,
                              hipStream_t stream)
{
  const float* x_in = (const float*)d_in[0];
  const float* Wqkv = (const float*)d_in[1];
  const float* bqkv = (const float*)d_in[2];
  const float* W1   = (const float*)d_in[3];
  const float* b1   = (const float*)d_in[4];
  const float* W2   = (const float*)d_in[5];
  const float* b2   = (const float*)d_in[6];
  const float* g1   = (const float*)d_in[7];
  const float* bt1  = (const float*)d_in[8];
  const float* g2   = (const float*)d_in[9];
  const float* bt2  = (const float*)d_in[10];
  const float* g3   = (const float*)d_in[11];
  const float* bt3  = (const float*)d_in[12];

  float* X = (float*)d_out;                               // [8192,512] fp32

  char* ws = (char*)d_ws;
  unsigned short* qkv    = (unsigned short*)(ws);                       // 16MB [8192,1024] bf16 (q,k)
  unsigned short* hbuf   = (unsigned short*)(ws + ((size_t)16<<20));    // 32MB [8192,2048] bf16
  unsigned short* Wm     = (unsigned short*)(ws + ((size_t)48<<20));    // 16MB [8,1024,1024] bf16
  float*          tmp    = (float*)         (ws + ((size_t)64<<20));    // 16MB [8192,512] fp32 (sa / ffn2 p0)
  float*          tmp2   = (float*)         (ws + ((size_t)80<<20));    // 16MB ffn2 p1
  unsigned short* Xb     = (unsigned short*)(ws + ((size_t)96<<20));    // 8MB  [8192,512] bf16
  unsigned short* XT     = (unsigned short*)(ws + ((size_t)104<<20));   // 8MB  [512,8192] bf16
  unsigned short* Wqkvb  = (unsigned short*)(ws + ((size_t)112<<20));   // 4MB  [4,1024,512]
  unsigned short* W1b    = (unsigned short*)(ws + ((size_t)118<<20));   // 8MB
  unsigned short* W2b    = (unsigned short*)(ws + ((size_t)126<<20));   // 8MB
  float*          dpart  = (float*)         (ws + ((size_t)134<<20));   // 2MB  [8][8][8][1024]
  float*          Dp     = (float*)         (ws + ((size_t)136<<20));   // 512KB [16][8][1024]

  // weight conversions (same work every call): one kernel, 3 segments
  cvt_all<<<(524288 + 2*1048576)/256, 256, 0, stream>>>(Wqkv, W1, W2, Wqkvb, W1b, W2b);
  init_x<<<NROWS, 256, 0, stream>>>(x_in, X, Xb);
  transpose_bf16<<<dim3(8,128), 256, 0, stream>>>(Xb, XT);

  for(int d=0; d<4; d++){
    // qk = X * Wqkv[0:1024]^T + bqkv   (128x128 dbuf, XCD-swizzled, 512 blocks)
    gemm_db<true,false,true,false,128><<<dim3(512), 256, 0, stream>>>(
        Xb, Wqkvb + (size_t)d*1024*EMB, bqkv + (size_t)d*1536, qkv,
        EMB, EMB, EMB, 1024, 0, 0, 0, 64, 8);

    // per-head per-j-tile softmax denominator partials (no atomics)
    qk_dsum<<<dim3(8, 8, 64), 256, 0, stream>>>(qkv, dpart);

    // averaged A + causal/pos re-softmax numerator -> Wm, Dp partials
    attn_w<<<dim3(136, NB), 256, 0, stream>>>(qkv, dpart, Wm, Dp);

    // sa = W @ x  (B = XT per batch, causal K limit), 128x64 dbuf, 512 blocks
    gemm_db<false,false,false,true,64><<<dim3(512), 256, 0, stream>>>(
        Wm, XT, nullptr, tmp,
        SEQ, SEQ, NROWS, EMB,
        (long long)SEQ*SEQ, 1024, (long long)SEQ*EMB, 8, 8);

    // x = LN2(LN1(x + sa/sum(Dp)))
    residual_ln2<<<NROWS, 256, 0, stream>>>(X, tmp, Dp,
        g1 + d*EMB, bt1 + d*EMB, g2 + d*EMB, bt2 + d*EMB, X, Xb);

    // h = relu(x*W1^T + b1)   (1024 blocks)
    gemm_db<true,true,true,false,128><<<dim3(1024), 256, 0, stream>>>(
        Xb, W1b + (size_t)d*FFD*EMB, b1 + (size_t)d*FFD, hbuf,
        EMB, EMB, EMB, FFD, 0, 0, 0, 64, 16);

    // ff = h*W2^T + b2, split-K=2 (partials tmp, tmp2; bias on z==0), 512 blocks
    gemm_db<false,false,true,false,128><<<dim3(512), 256, 0, stream>>>(
        hbuf, W2b + (size_t)d*EMB*FFD, b2 + (size_t)d*EMB, tmp,
        1024, FFD, FFD, EMB,
        1024, 1024, (long long)NROWS*EMB, 64, 4);

    // x = LN3(x + ff0 + ff1)
    residual_ln<<<NROWS, 256, 0, stream>>>(X, tmp, tmp2,
        g3 + d*EMB, bt3 + d*EMB, X, Xb);
    transpose_bf16<<<dim3(8,128), 256, 0, stream>>>(Xb, XT);
  }
}